// Round 3
// baseline (238.339 us; speedup 1.0000x reference)
//
#include <hip/hip_runtime.h>
#include <hip/hip_cooperative_groups.h>
#include <cmath>

namespace cg = cooperative_groups;

// act: (4, 4096, 4096) float32, GROUP_SIZE = 32
#define NELEM    (4ull * 4096ull * 4096ull)   // 67108864
#define NV4      (NELEM / 4ull)               // 16777216 float4s
#define NGROUPS  128
#define GRID     1024
#define BLK      256
#define NTHREADS ((size_t)GRID * BLK)         // 262144 (multiple of 1024)
#define ITERS    (NV4 / NTHREADS)             // 64

typedef float v4f __attribute__((ext_vector_type(4)));

// Single cooperative kernel:
//  phase 1: per-block abs-max partials (each block touches exactly 32 groups:
//           its threads cover float4 columns (bid&3)*256 .. +255 of the
//           1024-float4 row, fixed across grid-stride iterations)
//  grid.sync()
//  phase 2a: each block reduces the 256 partial rows sharing its residue
//            (32 KB from L2) and builds qstep = s/8, inv_s = 1/s (exact pow2)
//  phase 2b: quantize + non-temporal store (don't evict L3-resident input)
__global__ void __launch_bounds__(BLK, 4)
fused_quant(const float4* __restrict__ in, float4* __restrict__ out,
            float* __restrict__ exps_out, unsigned int* __restrict__ partials) {
    __shared__ unsigned int smax[32];
    __shared__ float2 ssc[32];

    const int tid = threadIdx.x;
    const int bid = blockIdx.x;
    const int res = bid & 3;            // which quarter of the row this block owns
    const int l   = tid >> 3;           // local group 0..31

    if (tid < 32) smax[tid] = 0u;
    __syncthreads();

    const size_t idx = (size_t)bid * BLK + tid;

    // ---- phase 1: local abs-max ----
    float m = 0.0f;
    #pragma unroll 4
    for (int t = 0; t < (int)ITERS; ++t) {
        float4 v = in[idx + (size_t)t * NTHREADS];
        m = fmaxf(m, fmaxf(fmaxf(fabsf(v.x), fabsf(v.y)),
                           fmaxf(fabsf(v.z), fabsf(v.w))));
    }
    atomicMax(&smax[l], __float_as_uint(m));   // non-neg floats order as uints
    __syncthreads();
    if (tid < 32) partials[bid * 32 + tid] = smax[tid];

    cg::this_grid().sync();

    // ---- phase 2a: reduce partials for this block's 32 groups ----
    if (tid < 32) smax[tid] = 0u;
    __syncthreads();
    {
        const int c = tid & 7;                 // 8 chunks of 32 blocks
        unsigned int mm = 0u;
        #pragma unroll
        for (int k = 0; k < 32; ++k) {
            const int b2 = res + 4 * (c * 32 + k);   // blocks with same residue
            mm = max(mm, partials[b2 * 32 + l]);
        }
        atomicMax(&smax[l], mm);
    }
    __syncthreads();
    if (tid < 32) {
        const float mf = __uint_as_float(smax[tid]);
        int e = 0;
        if (mf > 0.0f) { int e2; (void)frexpf(mf, &e2); e = e2 - 1; }  // exact floor(log2)
        ssc[tid] = make_float2(ldexpf(1.0f, e - 3),    // s/8
                               ldexpf(1.0f, -e));      // 1/s
        if (bid < 4) exps_out[res * 32 + tid] = (float)e;
    }
    __syncthreads();

    const float qstep = ssc[l].x;
    const float inv_s = ssc[l].y;

    // ---- phase 2b: quantize (rintf = round-half-even = jnp.round; all
    // scale factors are powers of two -> bit-exact) ----
    for (int t = 0; t < (int)ITERS; ++t) {
        const size_t i = idx + (size_t)t * NTHREADS;
        float4 v = in[i];
        v4f q;
        q.x = copysignf(rintf(fminf(fabsf(v.x) * inv_s, 1.0f) * 8.0f) * qstep, v.x);
        q.y = copysignf(rintf(fminf(fabsf(v.y) * inv_s, 1.0f) * 8.0f) * qstep, v.y);
        q.z = copysignf(rintf(fminf(fabsf(v.z) * inv_s, 1.0f) * 8.0f) * qstep, v.z);
        q.w = copysignf(rintf(fminf(fabsf(v.w) * inv_s, 1.0f) * 8.0f) * qstep, v.w);
        __builtin_nontemporal_store(q, (v4f*)&out[i]);
    }
}

extern "C" void kernel_launch(void* const* d_in, const int* in_sizes, int n_in,
                              void* d_out, int out_size, void* d_ws, size_t ws_size,
                              hipStream_t stream) {
    const float4* act = (const float4*)d_in[0];
    float4* q_out     = (float4*)d_out;
    float* exps_out   = (float*)d_out + NELEM;              // 128 floats at tail
    unsigned int* partials = (unsigned int*)d_ws;           // 1024*32*4 = 128 KB

    void* args[] = { (void*)&act, (void*)&q_out, (void*)&exps_out, (void*)&partials };
    hipLaunchCooperativeKernel(reinterpret_cast<void*>(fused_quant),
                               dim3(GRID), dim3(BLK), args, 0, stream);
}

// Round 4
// 137.620 us; speedup vs baseline: 1.7319x; 1.7319x over previous
//
#include <hip/hip_runtime.h>
#include <cmath>

// act: (4, 4096, 4096) float32, GROUP_SIZE = 32
#define NELEM     (4ull * 4096ull * 4096ull)   // 67108864
#define NV4       (NELEM / 4ull)               // 16777216 float4s
#define NGROUPS   128                          // 4096 / 32

#define P1_GRID   512
#define P1_BLK    1024
#define P1_STRIDE ((size_t)P1_GRID * P1_BLK)   // 524288 (multiple of 1024)
#define P1_ITERS  (NV4 / P1_STRIDE)            // 32

#define P2_GRID   2048
#define P2_BLK    256
#define P2_STRIDE ((size_t)P2_GRID * P2_BLK)   // 524288 (multiple of 1024)
#define P2_ITERS  (NV4 / P2_STRIDE)            // 32 (batched 4 -> 8 outer)

typedef float v4f __attribute__((ext_vector_type(4)));

// ---------------------------------------------------------------------------
// Pass 1: per-(block,group) partial abs-max. blockDim=1024 -> each thread's
// group g = tid>>3 is fixed across grid-stride iters. Partials stored
// TRANSPOSED (partials[g*P1_GRID + bid]) so pass2's reduction reads are
// contiguous. Normal caching loads on purpose: they warm L3 for pass 2.
// 512 blocks = 2 blocks/CU x 16 waves = 32 waves/CU (full occupancy).
__global__ void __launch_bounds__(P1_BLK)
pass1_max(const float4* __restrict__ in, unsigned int* __restrict__ partials) {
    __shared__ unsigned int smax[NGROUPS];
    const int tid = threadIdx.x;
    if (tid < NGROUPS) smax[tid] = 0u;
    __syncthreads();

    const size_t idx = (size_t)blockIdx.x * P1_BLK + tid;
    const int g = tid >> 3;                                 // 0..127

    float m = 0.0f;
    #pragma unroll 4
    for (int t = 0; t < (int)P1_ITERS; ++t) {
        float4 v = in[idx + (size_t)t * P1_STRIDE];
        m = fmaxf(m, fmaxf(fmaxf(fabsf(v.x), fabsf(v.y)),
                           fmaxf(fabsf(v.z), fabsf(v.w))));
    }
    atomicMax(&smax[g], __float_as_uint(m));   // non-neg floats order as uints
    __syncthreads();
    if (tid < NGROUPS)
        partials[(size_t)tid * P1_GRID + blockIdx.x] = smax[tid];
}

// ---------------------------------------------------------------------------
// Pass 2: prologue reduces this block's 32 group-columns from the partials
// (64 KB, L2/L3-resident, coalesced rows), computes exact pow-2 scales, then
// quantizes with 4-wide batched loads + non-temporal stores.
// q = copysign(rint(min(|a|*inv_s,1)*8) * (s/8), a); rintf = round-half-even
// = jnp.round; all scale factors are powers of two -> bit-exact vs numpy.
__global__ void __launch_bounds__(P2_BLK)
pass2_quant(const float4* __restrict__ in, float4* __restrict__ out,
            const unsigned int* __restrict__ partials,
            float* __restrict__ exps_out) {
    __shared__ unsigned int smax[32];
    __shared__ float2 ssc[32];

    const int tid = threadIdx.x;
    const int bid = blockIdx.x;
    const int res = bid & 3;            // which quarter of the 1024-f4 row
    const int l   = tid >> 3;           // local group 0..31 (g = res*32 + l)

    if (tid < 32) smax[tid] = 0u;
    __syncthreads();

    // ---- reduce partials for this block's 32 groups ----
    {
        const int c = tid & 7;          // 8 chunks of 64 partial-blocks
        const unsigned int* row = partials + (size_t)(res * 32 + l) * P1_GRID;
        unsigned int mm = 0u;
        #pragma unroll 8
        for (int k = 0; k < 64; ++k)
            mm = max(mm, row[c * 64 + k]);
        atomicMax(&smax[l], mm);
    }
    __syncthreads();
    if (tid < 32) {
        const float mf = __uint_as_float(smax[tid]);
        int e = 0;
        if (mf > 0.0f) { int e2; (void)frexpf(mf, &e2); e = e2 - 1; }  // exact floor(log2)
        ssc[tid] = make_float2(ldexpf(1.0f, e - 3),    // s/8
                               ldexpf(1.0f, -e));      // 1/s
        if (bid < 4) exps_out[res * 32 + tid] = (float)e;
    }
    __syncthreads();

    const float qstep = ssc[l].x;
    const float inv_s = ssc[l].y;
    const size_t idx = (size_t)bid * P2_BLK + tid;

    // ---- quantize: 4 independent loads in flight, then 4 NT stores ----
    #define QUANT1(v, q)                                                        \
        q.x = copysignf(rintf(fminf(fabsf(v.x) * inv_s, 1.0f) * 8.0f) * qstep, v.x); \
        q.y = copysignf(rintf(fminf(fabsf(v.y) * inv_s, 1.0f) * 8.0f) * qstep, v.y); \
        q.z = copysignf(rintf(fminf(fabsf(v.z) * inv_s, 1.0f) * 8.0f) * qstep, v.z); \
        q.w = copysignf(rintf(fminf(fabsf(v.w) * inv_s, 1.0f) * 8.0f) * qstep, v.w);

    for (int t = 0; t < (int)(P2_ITERS / 4); ++t) {
        const size_t i0 = idx + (size_t)(4 * t + 0) * P2_STRIDE;
        const size_t i1 = idx + (size_t)(4 * t + 1) * P2_STRIDE;
        const size_t i2 = idx + (size_t)(4 * t + 2) * P2_STRIDE;
        const size_t i3 = idx + (size_t)(4 * t + 3) * P2_STRIDE;
        float4 v0 = in[i0];
        float4 v1 = in[i1];
        float4 v2 = in[i2];
        float4 v3 = in[i3];
        v4f q0, q1, q2, q3;
        QUANT1(v0, q0) QUANT1(v1, q1) QUANT1(v2, q2) QUANT1(v3, q3)
        __builtin_nontemporal_store(q0, (v4f*)&out[i0]);
        __builtin_nontemporal_store(q1, (v4f*)&out[i1]);
        __builtin_nontemporal_store(q2, (v4f*)&out[i2]);
        __builtin_nontemporal_store(q3, (v4f*)&out[i3]);
    }
    #undef QUANT1
}

// ---------------------------------------------------------------------------
extern "C" void kernel_launch(void* const* d_in, const int* in_sizes, int n_in,
                              void* d_out, int out_size, void* d_ws, size_t ws_size,
                              hipStream_t stream) {
    const float* act = (const float*)d_in[0];
    float* q_out    = (float*)d_out;
    float* exps_out = q_out + NELEM;                        // 128 floats at tail
    unsigned int* partials = (unsigned int*)d_ws;           // 128*512*4 = 256 KB

    pass1_max<<<P1_GRID, P1_BLK, 0, stream>>>((const float4*)act, partials);
    pass2_quant<<<P2_GRID, P2_BLK, 0, stream>>>((const float4*)act, (float4*)q_out,
                                                partials, exps_out);
}